// Round 11
// baseline (378.351 us; speedup 1.0000x reference)
//
#include <hip/hip_runtime.h>
#include <hip/hip_fp16.h>

// SSIM, B=16, C=1, H=W=1024, 11x11 separable Gaussian.
// v10: v4 skeleton + CROSS-STEP SOFTWARE PIPELINE of the two exchange
// batches. Evidence (v7/v8/v9): kernel is DS-latency/chain bound, not
// VALU-issue bound -- v9 cut issue count 30% and got SLOWER.
// Reordered step t:
//   1) mu(t) from CARRIED V-exch results (issued at t-1)
//   2) d(t); ISSUE d-exch (10 bpermutes)
//   3) commit row t+1; issue prefetch row t+2; V-blur(t+1); ISSUE V-exch(t+1)
//   4) consume d-exch -> hp(t)   [V batch still in flight]
//   5) stats/COMB(t)             [covers carried V batch until next iter]
// Both DS waits now have 45-80 VALU ops of cover -> off the critical path.
// Also: iterations 84..87 (fully masked in v4) skipped via uniform guard;
// prefetch deepened to t+2 (~130-op cover). Math byte-identical to v4 fp32
// (packed half2 only on the bpermute WORDS, as verified in v4, absmax 0.0).
// launch_bounds(256,1): carries push VGPR ~115-125; v6 proved 128-cap
// spills, v8 proved 132 at (256,1) is spill-free. WRITE_SIZE = tripwire.

#define IMG_H 1024
#define IMG_W 1024
#define USEC   44                      // useful cols per wave
#define NSTRIP 24                      // 24*44 = 1056 >= 1024
#define BAND   64                      // output rows per wave
#define NBAND  16
#define NBATCH 16
#define NWAVES (NSTRIP * NBAND * NBATCH)   // 6144
#define NBLK   (NWAVES / 4)                // 1536 blocks of 4 waves

__device__ __forceinline__ unsigned fkey(float f) {
  unsigned b = __float_as_uint(f);
  return (b & 0x80000000u) ? ~b : (b | 0x80000000u);
}
__device__ __forceinline__ float funkey(unsigned k) {
  return (k & 0x80000000u) ? __uint_as_float(k & 0x7FFFFFFFu)
                           : __uint_as_float(~k);
}
__device__ __forceinline__ unsigned xlane_u(unsigned v, int addr) {
  // full-wave (64-lane) register crossbar; addr in bytes, lane = addr[7:2]
  return (unsigned)__builtin_amdgcn_ds_bpermute(addr, (int)v);
}
__device__ __forceinline__ __half2 u2h(unsigned u) { return *(__half2*)&u; }
__device__ __forceinline__ unsigned h2u(__half2 h) { return *(unsigned*)&h; }

__global__ void ssim_init(unsigned* __restrict__ ws) {
  ws[0] = 0u;           // sum S0*B0
  ws[1] = 0u;           // sum S0*B'   (C1 coefficient)
  ws[2] = 0u;           // sum B0*S'   (C2 coefficient)
  ws[3] = 0xFFFFFFFFu;  // min key
  ws[4] = 0u;           // max key
  ws[5] = 0u;           // done-counter
}

__global__ __launch_bounds__(256, 1)
void ssim_main(const float* __restrict__ img1, const float* __restrict__ img2,
               const float* __restrict__ kern, unsigned* __restrict__ ws,
               float* __restrict__ out) {
  __shared__ float redbuf[4][8];

  const int tid = threadIdx.x;
  const int lane = tid & 63;
  const int wv = tid >> 6;
  const int wid = blockIdx.x * 4 + wv;

  const int strip = wid % NSTRIP;
  const int rem = wid / NSTRIP;
  const int band = rem % NBAND;
  const int batch = rem / NBAND;

  const size_t boff = (size_t)batch * (IMG_H * IMG_W);
  const float* i1 = img1 + boff;
  const float* i2 = img2 + boff;

  // separable weights: g[j] = k2d[5][j] / sqrt(k2d[5][5]) (VGPRs; v7 showed
  // SGPR-pinning starves ILP)
  float g[11];
  #pragma unroll
  for (int j = 0; j < 11; ++j) g[j] = kern[55 + j] * rsqrtf(kern[60]);

  const int col = strip * USEC + lane - 10;    // absolute column of this lane
  const bool cok = (col >= 0) && (col < IMG_W);
  const int cidx = min(max(col, 0), IMG_W - 1);
  const bool oma = (lane >= 10) && (lane < 54) && (col < IMG_W); // output lane
  const int r0 = band * BAND;
  const int a4 = lane * 4;                     // bpermute self byte-address

  // rolling windows (statically indexed -> registers)
  float w1[11] = {}, w2[11] = {};
  float m1w[11] = {}, m2w[11] = {};
  float p11[11] = {}, p22[11] = {}, p12[11] = {};

  // pipeline carries
  unsigned vxl[5], vxr[5];                     // V-exch results in flight
  float V1c, V2c;                              // V centers for next mu
  float nv1, nv2;                              // prefetch buffer

  float acc0 = 0.f, aC1 = 0.f, aC2 = 0.f;
  float vmin = 1e30f, vmax = -1e30f;

  // ---- prologue: commit row 0 (rt = r0-10); prefetch row 1; V(0)+exch ----
  {
    int rin = r0 - 10;
    float a1 = 0.f, a2 = 0.f;
    if ((unsigned)rin < IMG_H) {
      a1 = i1[(size_t)rin * IMG_W + cidx];
      a2 = i2[(size_t)rin * IMG_W + cidx];
    }
    float v1 = cok ? a1 : 0.f;
    float v2 = cok ? a2 : 0.f;
    w1[0] = v1; w2[0] = v2;
    vmin = fminf(vmin, fminf(v1, v2));
    vmax = fmaxf(vmax, fmaxf(v1, v2));
  }
  {
    int rin = r0 - 9;
    if ((unsigned)rin < IMG_H) {
      nv1 = i1[(size_t)rin * IMG_W + cidx];
      nv2 = i2[(size_t)rin * IMG_W + cidx];
    } else { nv1 = 0.f; nv2 = 0.f; }
  }
  {
    // V(0): iteration-0 indexing ix = (1+j)%11 (only slot 0 is nonzero)
    float V1 = 0.f, V2 = 0.f;
    #pragma unroll
    for (int j = 0; j < 11; ++j) {
      int ix = (1 + j) % 11;
      V1 = fmaf(g[j], w1[ix], V1);
      V2 = fmaf(g[j], w2[ix], V2);
    }
    unsigned pv = h2u(__floats2half2_rn(V1, V2));
    #pragma unroll
    for (int o = 1; o <= 5; ++o) {
      vxl[o - 1] = xlane_u(pv, a4 - 4 * o);
      vxr[o - 1] = xlane_u(pv, a4 + 4 * o);
    }
    V1c = V1; V2c = V2;
  }

  #pragma unroll 1
  for (int m = 0; m < 8; ++m) {
    #pragma unroll
    for (int c = 0; c < 11; ++c) {
      const int t = m * 11 + c;                // step; img row rt = r0-10+t
      if (t < 84) {
        const int i6 = (c + 6) % 11;

        // 1) mu(t) at row rt-5 from CARRIED V-exch (lgkmcnt covers V batch
        //    only; it had hp+stats of the previous step as latency cover)
        float mu1 = g[5] * V1c, mu2 = g[5] * V2c;
        #pragma unroll
        for (int o = 1; o <= 5; ++o) {
          __half2 hl = u2h(vxl[o - 1]);
          __half2 hr = u2h(vxr[o - 1]);
          float sg = g[5 + o];                 // == g[5 - o] (symmetric)
          mu1 = fmaf(sg, __low2float(hl), mu1);
          mu1 = fmaf(sg, __low2float(hr), mu1);
          mu2 = fmaf(sg, __high2float(hl), mu2);
          mu2 = fmaf(sg, __high2float(hr), mu2);
        }
        m1w[c] = mu1; m2w[c] = mu2;

        // 2) d(t) at row rt-5 (0 outside image, matching zero-padded conv);
        //    ISSUE d-exch
        const bool drok = ((unsigned)(r0 - 15 + t) < IMG_H);
        float d1 = (drok && cok) ? (w1[i6] - mu1) : 0.f;
        float d2 = (drok && cok) ? (w2[i6] - mu2) : 0.f;
        unsigned pd = h2u(__floats2half2_rn(d1, d2));
        unsigned dxl[5], dxr[5];
        #pragma unroll
        for (int o = 1; o <= 5; ++o) {
          dxl[o - 1] = xlane_u(pd, a4 - 4 * o);
          dxr[o - 1] = xlane_u(pd, a4 + 4 * o);
        }

        // 3) commit row t+1; prefetch row t+2; V-blur(t+1); ISSUE V-exch
        //    (this block is the latency cover for the d batch)
        if (t < 83) {
          const int cn = (c + 1) % 11;
          float v1 = cok ? nv1 : 0.f;
          float v2 = cok ? nv2 : 0.f;
          w1[cn] = v1; w2[cn] = v2;
          vmin = fminf(vmin, fminf(v1, v2));   // pad zeros: negligible vs min
          vmax = fmaxf(vmax, fmaxf(v1, v2));
          if (t < 82) {
            int rin = r0 - 8 + t;              // row t+2
            if ((unsigned)rin < IMG_H) {
              nv1 = i1[(size_t)rin * IMG_W + cidx];
              nv2 = i2[(size_t)rin * IMG_W + cidx];
            } else { nv1 = 0.f; nv2 = 0.f; }
          }
          float V1 = 0.f, V2 = 0.f;
          #pragma unroll
          for (int j = 0; j < 11; ++j) {
            int ix = (cn + 1 + j) % 11;        // rows t-9..t+1
            V1 = fmaf(g[j], w1[ix], V1);
            V2 = fmaf(g[j], w2[ix], V2);
          }
          unsigned pv = h2u(__floats2half2_rn(V1, V2));
          #pragma unroll
          for (int o = 1; o <= 5; ++o) {
            vxl[o - 1] = xlane_u(pv, a4 - 4 * o);  // old values consumed in 1)
            vxr[o - 1] = xlane_u(pv, a4 + 4 * o);
          }
          V1c = V1; V2c = V2;
        }

        // 4) consume d-exch -> hp(t)  (V batch stays in flight)
        float h11 = (g[5] * d1) * d1;
        float h22 = (g[5] * d2) * d2;
        float h12 = (g[5] * d1) * d2;
        #pragma unroll
        for (int o = 1; o <= 5; ++o) {
          __half2 hl = u2h(dxl[o - 1]);
          __half2 hr = u2h(dxr[o - 1]);
          float l1 = __low2float(hl), l2 = __high2float(hl);
          float r1 = __low2float(hr), r2 = __high2float(hr);
          float u = g[5 + o];                  // == g[5 - o]
          h11 = fmaf(u, fmaf(l1, l1, r1 * r1), h11);
          h22 = fmaf(u, fmaf(l2, l2, r2 * r2), h22);
          h12 = fmaf(u, fmaf(l1, l2, r1 * r2), h12);
        }
        p11[c] = h11; p22[c] = h22; p12[c] = h12;

        // 5) output row rt-10 (valid steps 20..83)
        if (t >= 20) {
          float s11 = 0.f, s22 = 0.f, s12 = 0.f;
          #pragma unroll
          for (int j = 0; j < 11; ++j) {
            float gj = g[j];
            s11 = fmaf(gj, p11[(c + 1 + j) % 11], s11);
            s22 = fmaf(gj, p22[(c + 1 + j) % 11], s22);
            s12 = fmaf(gj, p12[(c + 1 + j) % 11], s12);
          }
          float M1 = m1w[i6], M2 = m2w[i6];

          float s1 = s11 + 1.f;                // sigma1_sq
          float s2 = s22 + 1.f;                // sigma2_sq
          float sv = s12 + 1.f;                // sigma12
          float a = 2.f * sv;
          float b = s1 + s2;                   // >= 2 on valid lanes
          float rb = __builtin_amdgcn_rcpf(b);
          float S0 = a * rb;
          float Sp = (b - a) * rb * rb;        // dS/dC2
          float m12 = fmaf(M1, M2, 1.f);
          float nb = 2.f * m12;
          float N1 = nb * nb;
          float ms = fmaf(M1, M1, fmaf(M2, M2, 2.f));
          float Dv = ms * ms;                  // >= 4 on valid lanes
          float rD = __builtin_amdgcn_rcpf(Dv);
          float B0 = N1 * rD;
          float Bp = (Dv - N1) * rD * rD;      // dB/dC1
          float t0v = S0 * B0, t1v = S0 * Bp, t2v = B0 * Sp;
          acc0 += oma ? t0v : 0.f;             // select blocks NaN from halos
          aC1 += oma ? t1v : 0.f;
          aC2 += oma ? t2v : 0.f;
        }
      }
    }
  }

  // wave reduction (64 lanes), then block partials via tiny LDS
  #pragma unroll
  for (int off = 32; off > 0; off >>= 1) {
    acc0 += __shfl_down(acc0, off);
    aC1 += __shfl_down(aC1, off);
    aC2 += __shfl_down(aC2, off);
    vmin = fminf(vmin, __shfl_down(vmin, off));
    vmax = fmaxf(vmax, __shfl_down(vmax, off));
  }
  if (lane == 0) {
    redbuf[wv][0] = acc0; redbuf[wv][1] = aC1; redbuf[wv][2] = aC2;
    redbuf[wv][3] = vmin; redbuf[wv][4] = vmax;
  }
  __syncthreads();
  if (tid == 0) {
    float t0 = 0.f, t1 = 0.f, t2 = 0.f, mn = 1e30f, mx = -1e30f;
    #pragma unroll
    for (int w2 = 0; w2 < 4; ++w2) {
      t0 += redbuf[w2][0]; t1 += redbuf[w2][1]; t2 += redbuf[w2][2];
      mn = fminf(mn, redbuf[w2][3]); mx = fmaxf(mx, redbuf[w2][4]);
    }
    float* wsF = (float*)ws;
    atomicAdd(&wsF[0], t0);
    atomicAdd(&wsF[1], t1);
    atomicAdd(&wsF[2], t2);
    atomicMin(&ws[3], fkey(mn));
    atomicMax(&ws[4], fkey(mx));

    // finalize in the last block (v6/v7/v9-validated done-counter)
    __threadfence();                           // device-scope: order ws ops
    unsigned done = atomicAdd(&ws[5], 1u);
    if (done == gridDim.x - 1) {
      float s0 = atomicAdd(&wsF[0], 0.f);      // device-scope atomic reads
      float sc1 = atomicAdd(&wsF[1], 0.f);
      float sc2 = atomicAdd(&wsF[2], 0.f);
      unsigned mnk = atomicMin(&ws[3], 0xFFFFFFFFu);
      unsigned mxk = atomicMax(&ws[4], 0u);
      float vr = funkey(mxk) - funkey(mnk) + 1e-5f;
      float c1 = 0.01f * vr; c1 *= c1;
      float c2 = 0.03f * vr; c2 *= c2;
      float mean = (s0 + c1 * sc1 + c2 * sc2) * (1.0f / 16777216.0f);
      out[0] = 1.f - mean;
    }
  }
}

extern "C" void kernel_launch(void* const* d_in, const int* in_sizes, int n_in,
                              void* d_out, int out_size, void* d_ws, size_t ws_size,
                              hipStream_t stream) {
  const float* img1 = (const float*)d_in[0];
  const float* img2 = (const float*)d_in[1];
  const float* kern = (const float*)d_in[2];
  unsigned* ws = (unsigned*)d_ws;
  float* out = (float*)d_out;
  (void)in_sizes; (void)n_in; (void)out_size; (void)ws_size;

  hipLaunchKernelGGL(ssim_init, dim3(1), dim3(1), 0, stream, ws);
  hipLaunchKernelGGL(ssim_main, dim3(NBLK), dim3(256), 0, stream,
                     img1, img2, kern, ws, out);
}